// Round 1
// 134.115 us; speedup vs baseline: 1.0029x; 1.0029x over previous
//
#include <hip/hip_runtime.h>
#include <hip/hip_bf16.h>

// Conv 3x3, C_IN=128, C_OUT=256, H=W=256, pad=1, stride=1, batch=1.
// R8: one block per CU. 256 blocks x 512 threads; block tile = 256co x 256sp (full
//     output row). B = full padded xb row (258x128, 66 KB) staged once per kh;
//     A = full 256x128 weight plane per khw (64 KB). 9 barrier pairs per block
//     total (vs 36 block-phases/CU in R7), 1024 MFMA per CU-phase. 8 waves of
//     64co x 128sp -> DS fragment traffic (384 b128/CU-phase) < MFMA pipe time.
//     LDS 131.6 KB -> 1 block/CU, 2 waves/SIMD. XCD-chunked h-swizzle for B reuse
//     in per-XCD L2. Staging/swizzle scheme byte-identical to R7 (verified).

typedef short bf16x8 __attribute__((ext_vector_type(8)));    // 8 bf16 = 4 VGPRs
typedef float f32x4 __attribute__((ext_vector_type(4)));
typedef unsigned short u16x4 __attribute__((ext_vector_type(4)));
typedef unsigned short u16x8 __attribute__((ext_vector_type(8)));

#define CIN   128
#define COUT  256
#define HH    256
#define WW    256
#define HP    258                 // padded
#define ROWP  (HP * CIN)          // padded row stride in elems = 33024

static __device__ __forceinline__ unsigned short f2bf(float v) {
    __hip_bfloat16 b = __float2bfloat16(v);
    return *reinterpret_cast<unsigned short*>(&b);
}

static __device__ __forceinline__ void gload_lds16(const unsigned short* g, unsigned short* l) {
    __builtin_amdgcn_global_load_lds(
        (const __attribute__((address_space(1))) unsigned int*)g,
        (__attribute__((address_space(3))) unsigned int*)l, 16, 0, 0);
}

// ---------------- dispatch 1: fused prepass (edge zero + wreorder + xpose) -----------
// grid: 1024 blocks x 256 threads (one 64-w xpose tile per block) -- unchanged from R7
__global__ __launch_bounds__(256) void prep_kernel(const float* __restrict__ x,
                                                   const float* __restrict__ w,
                                                   unsigned short* __restrict__ xb,
                                                   unsigned short* __restrict__ wr) {
    int bid = blockIdx.x;
    int t   = threadIdx.x;

    // (a) edge zeroing: blocks 0..64 cover the 16448 vec8 border tasks
    if (bid < 65) {
        int i = bid * 256 + t;
        if (i < 16448) {
            u16x8 z = {0, 0, 0, 0, 0, 0, 0, 0};
            int off;
            if (i < 8256) {
                int r   = (i >= 4128) ? 1 : 0;
                int rem = i - r * 4128;
                off = (r * 257) * ROWP + rem * 8;
            } else {
                int j   = i - 8256;           // 0..8191
                int col = j >> 12;            // 0 or 1
                int rem = j & 4095;
                int hp  = (rem >> 4) + 1;     // 1..256
                int c8  = rem & 15;
                off = hp * ROWP + (col * 257) * CIN + c8 * 8;
            }
            *(u16x8*)(&xb[off]) = z;
        }
    }

    // (b) weight reorder: blocks 0..127, one thread per (co,ci), coalesced
    if (bid < 128) {
        int p = bid * 256 + t;    // 0..32767 = co*128+ci
        const float* src = w + p * 9;
        #pragma unroll
        for (int khw = 0; khw < 9; ++khw)
            wr[khw * (COUT * CIN) + p] = f2bf(src[khw]);
    }

    // (c) xpose: NCHW fp32 -> padded NHWC bf16, one 64-w tile per block
    int h  = bid >> 2;
    int w0 = (bid & 3) * 64;
    __shared__ unsigned short tile[CIN * 72];   // [ci][w], w padded 64->72

    int wq  = t & 15;          // 16 * float4 = 64 w
    int cib = t >> 4;          // 16 ci per pass
    for (int c0 = 0; c0 < CIN; c0 += 16) {
        int ci = c0 + cib;
        float4 v = *(const float4*)(x + ci * (HH * WW) + h * WW + w0 + wq * 4);
        u16x4 p;
        p.x = f2bf(v.x); p.y = f2bf(v.y); p.z = f2bf(v.z); p.w = f2bf(v.w);
        *(u16x4*)(&tile[ci * 72 + wq * 4]) = p;
    }
    __syncthreads();

    for (int it = 0; it < 4; ++it) {
        int idx = it * 256 + t;       // 0..1023
        int ww_ = idx & 63;           // varies within wave (conflict-free LDS reads)
        int c8  = idx >> 6;           // 0..15, wave-uniform
        u16x8 o;
        #pragma unroll
        for (int j = 0; j < 8; ++j)
            o[j] = tile[(c8 * 8 + j) * 72 + ww_];
        int dst = ((h + 1) * HP + (w0 + ww_ + 1)) * CIN + c8 * 8;
        *(u16x8*)(&xb[dst]) = o;
    }
}

// ---------------- dispatch 2: implicit-GEMM MFMA conv, one block per CU --------------
// block tile: 256 co x 256 spatial (full row h). 8 waves (4 co-quarters x 2 sp-halves),
// each 64co x 128sp. Per phase (khw): A plane 256x128 staged; B full padded row staged
// once per kh. 128 MFMA/wave per phase, 9 phases total.
// Bw[col 0..257][ci 0..127]: 16B chunk c of col stored at slot c^(col&15).
// As[row 0..255][ci 0..127]: 16B chunk c of row stored at slot c^(row&15).
// Frag reads hit slot*4 mod 32 banks -> 2-way aliasing (free).
__global__ __launch_bounds__(512, 2) void conv_mfma_kernel(const unsigned short* __restrict__ xb,
                                                           const unsigned short* __restrict__ wr,
                                                           const float* __restrict__ bias,
                                                           float* __restrict__ out) {
    __shared__ unsigned short Bw[258 * 128];   // 66048 B
    __shared__ unsigned short As[256 * 128];   // 65536 B

    // XCD-chunked bijective swizzle: 256 blocks, 8 XCDs -> 32 consecutive rows per XCD
    // (neighboring h share xb rows in the per-XCD L2).
    int bid = blockIdx.x;
    int h   = (bid & 7) * 32 + (bid >> 3);     // 0..255, one output row per block

    int t    = threadIdx.x;     // 0..511
    int wave = t >> 6;
    int lane = t & 63;
    int wm   = wave >> 1;       // co quarter (0..3), 64 co each
    int wn   = wave & 1;        // spatial half (0/1), 128 sp each
    int quad = lane >> 4;
    int l16  = lane & 15;

    f32x4 acc[4][8];
    #pragma unroll
    for (int mi = 0; mi < 4; ++mi)
        #pragma unroll
        for (int ni = 0; ni < 8; ++ni)
            acc[mi][ni] = (f32x4){0.f, 0.f, 0.f, 0.f};

    for (int kh = 0; kh < 3; ++kh) {
        const unsigned short* xrow = xb + (size_t)(h + kh) * ROWP;
        for (int kw = 0; kw < 3; ++kw) {
            int khw = kh * 3 + kw;
            __syncthreads();   // previous phase's LDS consumers done
            if (kw == 0) {
                // stage B window: 258 cols x 16 chunks = 4128 segs of 16B
                #pragma unroll
                for (int it = 0; it < 8; ++it) {
                    int seg = it * 512 + t;
                    int col = seg >> 4;
                    int s   = seg & 15;
                    int c   = s ^ (col & 15);
                    gload_lds16(xrow + col * CIN + c * 8, &Bw[seg * 8]);
                }
                if (t < 32) {
                    int seg = 4096 + t;
                    int col = seg >> 4;
                    int s   = seg & 15;
                    int c   = s ^ (col & 15);
                    gload_lds16(xrow + col * CIN + c * 8, &Bw[seg * 8]);
                }
            }
            // stage A plane for this khw: 256 rows x 16 chunks = 4096 segs
            {
                const unsigned short* wsrc = wr + (size_t)khw * (COUT * CIN);
                #pragma unroll
                for (int it = 0; it < 8; ++it) {
                    int seg = it * 512 + t;
                    int r   = seg >> 4;
                    int s   = seg & 15;
                    int c   = s ^ (r & 15);
                    gload_lds16(wsrc + r * CIN + c * 8, &As[seg * 8]);
                }
            }
            __syncthreads();   // DMA drained (compiler emits vmcnt(0) before barrier)
            // compute: 4 kk x 32 MFMA = 128 MFMA per wave per barrier pair
            #pragma unroll
            for (int kk = 0; kk < 4; ++kk) {
                int chunk = kk * 4 + quad;
                bf16x8 af[4], bfr[8];
                #pragma unroll
                for (int mi = 0; mi < 4; ++mi) {
                    int row = wm * 64 + mi * 16 + l16;     // row&15 == l16
                    af[mi] = *(bf16x8*)(&As[row * 128 + (chunk ^ l16) * 8]);
                }
                #pragma unroll
                for (int ni = 0; ni < 8; ++ni) {
                    int col = wn * 128 + ni * 16 + l16 + kw;
                    bfr[ni] = *(bf16x8*)(&Bw[col * 128 + (chunk ^ (col & 15)) * 8]);
                }
                #pragma unroll
                for (int mi = 0; mi < 4; ++mi)
                    #pragma unroll
                    for (int ni = 0; ni < 8; ++ni)
                        acc[mi][ni] = __builtin_amdgcn_mfma_f32_16x16x32_bf16(
                            af[mi], bfr[ni], acc[mi][ni], 0, 0, 0);
            }
        }
    }

    // epilogue: C/D layout col(spatial)=lane&15, row(co)=quad*4+reg
    int sp0 = wn * 128 + l16;
    #pragma unroll
    for (int mi = 0; mi < 4; ++mi) {
        #pragma unroll
        for (int r = 0; r < 4; ++r) {
            int co = wm * 64 + mi * 16 + quad * 4 + r;
            float b = bias[co];
            float* orow = out + (size_t)co * (HH * WW) + h * WW + sp0;
            #pragma unroll
            for (int ni = 0; ni < 8; ++ni)
                orow[ni * 16] = acc[mi][ni][r] + b;
        }
    }
}

extern "C" void kernel_launch(void* const* d_in, const int* in_sizes, int n_in,
                              void* d_out, int out_size, void* d_ws, size_t ws_size,
                              hipStream_t stream) {
    const float* x    = (const float*)d_in[0];   // [1,128,256,256]
    const float* w    = (const float*)d_in[1];   // [256,128,3,3]
    const float* bias = (const float*)d_in[2];   // [256]
    float* out        = (float*)d_out;           // [1,256,256,256]

    unsigned short* xb = (unsigned short*)d_ws;              // 258*258*128 bf16 = 17,040,384 B
    unsigned short* wr = xb + (size_t)HP * HP * CIN;         // 9*256*128 bf16  =    589,824 B

    prep_kernel<<<dim3(1024), dim3(256), 0, stream>>>(x, w, xb, wr);
    conv_mfma_kernel<<<dim3(256), dim3(512), 0, stream>>>(xb, wr, bias, out);
}